// Round 10
// baseline (3592.826 us; speedup 1.0000x reference)
//
#include <hip/hip_runtime.h>
#include <stdint.h>

// 3-layer LSTM (H=64, B=256, S=4096, DIN=1) + linear head.
// One block/batch element; 768 thr = 3 groups of 256 (group = layer).
// R10 restructure: per tick each group does ONLY its recurrent Whh matvec
// (32 weight dwords/thread hot -> below any VGPR budget, no AGPR-copy tax).
// The inter-layer matvecs Wih1·h0 and Wih2·h1 are batched 16 steps and run
// as MFMA GEMMs (16x16x32_f16, M=16 steps, N=256 rows, K=64) on the matrix
// pipe every 16 ticks, results staged in LDS (Xg). Skews: l0@T, l1@T-18,
// l2@T-36, y@T-37. h histories in 32-slot LDS rings.

#define SQ 4096
#define HH 64
#define NB 256

typedef _Float16 h2    __attribute__((ext_vector_type(2)));
typedef _Float16 f16x8 __attribute__((ext_vector_type(8)));
typedef float    f32x4 __attribute__((ext_vector_type(4)));
typedef uint32_t uv8   __attribute__((ext_vector_type(8)));

__device__ __forceinline__ h2 bch2(uint32_t u) { return __builtin_bit_cast(h2, u); }

template<int CTRL>
__device__ __forceinline__ float fdpp(float v) {
    return __builtin_bit_cast(float,
        __builtin_amdgcn_mov_dpp(__builtin_bit_cast(int, v), CTRL, 0xF, 0xF, true));
}
#define DPP_XOR1 0xB1
#define DPP_XOR2 0x4E
#define DPP_XOR3 0x1B
#define DPP_ROR4 0x124
#define DPP_ROR8 0x128

__device__ __forceinline__ float dotseg(uv8 w, uint4 a, uint4 b, float acc) {
    acc = __builtin_amdgcn_fdot2(bch2(w[0]), bch2(a.x), acc, false);
    acc = __builtin_amdgcn_fdot2(bch2(w[1]), bch2(a.y), acc, false);
    acc = __builtin_amdgcn_fdot2(bch2(w[2]), bch2(a.z), acc, false);
    acc = __builtin_amdgcn_fdot2(bch2(w[3]), bch2(a.w), acc, false);
    acc = __builtin_amdgcn_fdot2(bch2(w[4]), bch2(b.x), acc, false);
    acc = __builtin_amdgcn_fdot2(bch2(w[5]), bch2(b.y), acc, false);
    acc = __builtin_amdgcn_fdot2(bch2(w[6]), bch2(b.z), acc, false);
    acc = __builtin_amdgcn_fdot2(bch2(w[7]), bch2(b.w), acc, false);
    return acc;
}

// ---- prep: fp32 weights -> packed fp16 in ws (regions of 16384 halfs) ----
// region 0: Whh0 | 1: Wih1 | 2: Whh1 | 3: Wih2 | 4: Whh2
__global__ void prep_weights(const float* __restrict__ Whh0,
                             const float* __restrict__ Wih1,
                             const float* __restrict__ Whh1,
                             const float* __restrict__ Wih2,
                             const float* __restrict__ Whh2,
                             uint16_t* __restrict__ wsh) {
    const int i = blockIdx.x * 256 + threadIdx.x;        // 0..81919
    const int region = i >> 14;
    const int off = i & 16383;
    const float* src = (region == 0) ? Whh0 : (region == 1) ? Wih1
                     : (region == 2) ? Whh1 : (region == 3) ? Wih2 : Whh2;
    _Float16 v = (_Float16)src[off];
    wsh[i] = __builtin_bit_cast(uint16_t, v);
}

__global__ __launch_bounds__(768, 2) void lstm3_fused(
    const float* __restrict__ x,
    const float* __restrict__ Wih0,
    const float* __restrict__ bih0, const float* __restrict__ bhh0,
    const float* __restrict__ bih1, const float* __restrict__ bhh1,
    const float* __restrict__ bih2, const float* __restrict__ bhh2,
    const float* __restrict__ Wlin, const float* __restrict__ blin,
    const uint16_t* __restrict__ wsh,
    float* __restrict__ out)
{
    const int b    = blockIdx.x;
    const int tid  = threadIdx.x;
    const int grp  = tid >> 8;          // layer 0,1,2
    const int k    = tid & 255;
    const int u    = k >> 2;            // hidden unit
    const int qt   = k & 3;             // col quarter AND final gate index
    const int row  = qt * HH + u;       // this thread's final gate row
    const int lane = tid & 63;
    const int wv   = k >> 6;            // wave within group

    __shared__ __align__(16) float xrow[SQ];
    __shared__ __align__(16) _Float16 ring[3][32][HH];    // h history per layer
    __shared__ __align__(16) _Float16 Xgh[2][2][16][256]; // [L-1][buf][t&15][row]
    __shared__ __align__(16) float ybuf[2][16];

    for (int i = tid; i < SQ; i += 768) xrow[i] = x[b * SQ + i];
    ((uint4*)ring)[tid] = make_uint4(0, 0, 0, 0);         // 12288 B = 768 uint4
    if (tid < 32) ((float*)ybuf)[tid] = 0.f;

    // ---- recurrent Whh weights: 4 gate-row segments, packed fp16 ----
    const int regW = grp * 2;                             // 0,2,4
    auto seg = [&](int g) -> uv8 {
        const uint4* p = (const uint4*)(wsh + regW * 16384 + (g * HH + u) * HH + 16 * qt);
        uint4 a = p[0], c = p[1];
        uv8 r = { a.x, a.y, a.z, a.w, c.x, c.y, c.z, c.w };
        return r;
    };
    uv8 wA0 = seg(0), wA1 = seg(1), wA2 = seg(2), wA3 = seg(3);

    // ---- B-frags for the batched Wih GEMM (G1: Wih1, G2: Wih2) ----
    // B[k][n]: n = lane&15 (-> row r), k = (lane>>4)*8+j (-> col u). B = Wih^T.
    f16x8 bfr[4][2];
    if (grp != 0) {
        const uint16_t* base = wsh + ((grp == 1) ? 1 : 3) * 16384;
#pragma unroll
        for (int i = 0; i < 4; ++i) {
            const int r = (wv * 4 + i) * 16 + (lane & 15);
#pragma unroll
            for (int kt = 0; kt < 2; ++kt) {
                uint4 t = *(const uint4*)(base + r * HH + kt * 32 + (lane >> 4) * 8);
                bfr[i][kt] = __builtin_bit_cast(f16x8, t);
            }
        }
    } else {
#pragma unroll
        for (int i = 0; i < 4; ++i) { bfr[i][0] = (f16x8)(_Float16)0; bfr[i][1] = (f16x8)(_Float16)0; }
    }

    float bias = 0.f, wih0 = 0.f, wlin_u = 0.f;
    if (grp == 0) { bias = bih0[row] + bhh0[row]; wih0 = Wih0[row]; }
    else if (grp == 1) bias = bih1[row] + bhh1[row];
    else { bias = bih2[row] + bhh2[row]; if (qt == 0) wlin_u = Wlin[u]; }
    const float blin_v = blin[0];

    const bool b0c = qt & 1, b1c = (qt >> 1) & 1;
    const float s1 = (qt == 2) ? 2.f : 1.f;   // tanh = 2*sigm(2x)-1 for gate g
    const float o1 = (qt == 2) ? 1.f : 0.f;
    float cc = 0.f;                           // cell state (leaders qt==0)

    __syncthreads();

    // GEMM burst: Xg[plane][w&1] = (ring[src] window w) x Wih^T, 16x256
    auto gemm = [&](int src, int plane, int w) {
        const int buf = w & 1;
        const uint4* rb = (const uint4*)&ring[src][16 * buf + (lane & 15)][0];
        f16x8 A0 = __builtin_bit_cast(f16x8, rb[lane >> 4]);       // k 0..31
        f16x8 A1 = __builtin_bit_cast(f16x8, rb[4 + (lane >> 4)]); // k 32..63
        const f32x4 zz = {0.f, 0.f, 0.f, 0.f};
#pragma unroll
        for (int i = 0; i < 4; ++i) {
            f32x4 d = __builtin_amdgcn_mfma_f32_16x16x32_f16(A0, bfr[i][0], zz, 0, 0, 0);
            d = __builtin_amdgcn_mfma_f32_16x16x32_f16(A1, bfr[i][1], d, 0, 0, 0);
            const int r = (wv * 4 + i) * 16 + (lane & 15);
            _Float16* xg = &Xgh[plane][buf][(lane >> 4) * 4][r];
            xg[0]       = (_Float16)d[0];
            xg[256]     = (_Float16)d[1];
            xg[2 * 256] = (_Float16)d[2];
            xg[3 * 256] = (_Float16)d[3];
        }
    };

    for (int T = 0; T < SQ + 38; ++T) {
        const int tg = T - 18 * grp;          // skew 0 / 18 / 36
        float yv = 0.f;

        if (tg >= 0 && tg < SQ) {
            // recurrent dot: 4 gate rows x 16 cols of Whh . h_own[tg-1]
            const uint4* hp = (const uint4*)&ring[grp][(tg - 1) & 31][0];
            const uint4 a0 = hp[2 * qt], a1 = hp[2 * qt + 1];
            float p0 = dotseg(wA0, a0, a1, 0.f);
            float p1 = dotseg(wA1, a0, a1, 0.f);
            float p2 = dotseg(wA2, a0, a1, 0.f);
            float p3 = dotseg(wA3, a0, a1, 0.f);

            // quad transpose-reduce: lane qt ends with full sum of gate qt
            float k0 = (b0c ? p1 : p0) + fdpp<DPP_XOR1>(b0c ? p0 : p1);
            float k1 = (b0c ? p3 : p2) + fdpp<DPP_XOR1>(b0c ? p2 : p3);
            float g  = (b1c ? k1 : k0) + fdpp<DPP_XOR2>(b1c ? k0 : k1);
            g += bias;
            if (grp == 0) g += wih0 * xrow[tg];
            else          g += (float)Xgh[grp - 1][(tg >> 4) & 1][tg & 15][row];

            float t = 1.f / (1.f + __expf(-s1 * g));
            const float act = s1 * t - o1;    // sigm for i,f,o; tanh for g
            const float v1 = fdpp<DPP_XOR1>(act);
            const float v2 = fdpp<DPP_XOR2>(act);
            const float v3 = fdpp<DPP_XOR3>(act);

            if (qt == 0) {
                cc = v1 * cc + act * v2;      // sigm(f)*c + sigm(i)*tanh(g)
                float tc = fminf(fmaxf(cc, -15.f), 15.f);
                float e  = __expf(-2.f * tc);
                float h  = v3 * ((1.f - e) / (1.f + e));   // sigm(o)*tanh(c)
                ring[grp][tg & 31][u] = (_Float16)h;
                if (grp == 2) yv = wlin_u * h;
                if (tg == SQ - 1) {
                    out[NB * SQ + grp * NB * HH + b * HH + u] = h;
                    out[NB * SQ + 3 * NB * HH + grp * NB * HH + b * HH + u] = cc;
                }
            }
        }

        if (grp == 2) {
            yv += fdpp<DPP_XOR1>(yv);
            yv += fdpp<DPP_XOR2>(yv);
            yv += fdpp<DPP_ROR4>(yv);
            yv += fdpp<DPP_ROR8>(yv);
            if ((k & 15) == 0) ybuf[T & 1][k >> 4] = yv;
        }
        if (grp == 0 && u == HH - 1) {
            const int sy = T - 37;
            if (sy >= 0 && sy < SQ) {
                const float4 v = ((const float4*)ybuf[(T - 1) & 1])[qt];
                float s = (v.x + v.y) + (v.z + v.w);
                s += fdpp<DPP_XOR1>(s);
                s += fdpp<DPP_XOR2>(s);
                if (qt == 3) out[b * SQ + sy] = s + blin_v;
            }
        }

        // GEMM bursts (wave-uniform conditions)
        if (grp == 1 && (T & 15) == 0 && T >= 16 && T <= SQ)
            gemm(0, 0, (T >> 4) - 1);
        if (grp == 2 && ((T - 2) & 15) == 0 && T >= 34 && T <= SQ + 18)
            gemm(1, 1, (T >> 4) - 2);

        __syncthreads();
    }
}

extern "C" void kernel_launch(void* const* d_in, const int* in_sizes, int n_in,
                              void* d_out, int out_size, void* d_ws, size_t ws_size,
                              hipStream_t stream) {
    const float* x    = (const float*)d_in[0];
    const float* Wih0 = (const float*)d_in[1];
    const float* Whh0 = (const float*)d_in[2];
    const float* bih0 = (const float*)d_in[3];
    const float* bhh0 = (const float*)d_in[4];
    const float* Wih1 = (const float*)d_in[5];
    const float* Whh1 = (const float*)d_in[6];
    const float* bih1 = (const float*)d_in[7];
    const float* bhh1 = (const float*)d_in[8];
    const float* Wih2 = (const float*)d_in[9];
    const float* Whh2 = (const float*)d_in[10];
    const float* bih2 = (const float*)d_in[11];
    const float* bhh2 = (const float*)d_in[12];
    const float* Wlin = (const float*)d_in[13];
    const float* blin = (const float*)d_in[14];
    float* out = (float*)d_out;
    uint16_t* wsh = (uint16_t*)d_ws;

    prep_weights<<<320, 256, 0, stream>>>(Whh0, Wih1, Whh1, Wih2, Whh2, wsh);
    lstm3_fused<<<NB, 768, 0, stream>>>(x, Wih0, bih0, bhh0,
                                        bih1, bhh1, bih2, bhh2,
                                        Wlin, blin, wsh, out);
}